// Round 3
// baseline (5744.291 us; speedup 1.0000x reference)
//
#include <hip/hip_runtime.h>

#define T_STEPS 256
#define ISZ 16
#define HID 40
#define EPB 8            // batch elems per block
#define NTHR 512

__device__ __forceinline__ float sigm(float v)  { return 1.0f / (1.0f + __expf(-v)); }
__device__ __forceinline__ float tanh_f(float v){ return 1.0f - 2.0f / (__expf(2.0f * v) + 1.0f); }

// Decomposition: 4 stripes of 128 lanes (wave-aligned roles), lanes 0-119 of
// each stripe own one gate-row *projection part*:
//   stripe 0: layer0 input-proj  (W_ih0 row, K=16, reads Lx)
//   stripe 1: layer0 hidden-proj (W_hh0 row, K=40, reads H0s)
//   stripe 2: layer1 input-proj  (W_ih1 row, K=40, reads H0s)
//   stripe 3: layer1 hidden-proj (W_hh1 row, K=40, reads H1s)
// Per-lane weights = <=40 floats -> resident in VGPRs under launch_bounds(512,4)
// (round-2 lesson: 136 floats/lane made the compiler re-fetch weights from L2
// every step; 96-VGPR kernel at 1 wave/SIMD was latency-bound at 39% VALUBusy).
// Layers run skewed: iteration t computes h0[t] (L0) and h1[t-1] (L1)
// concurrently -> 2 barriers/step. Epilogue iteration t=256 finishes h1[255].
// Grid 512 blocks x 512 thr, 2 blocks/CU, 16 waves/CU for latency hiding.
__global__ __launch_bounds__(NTHR, 4)
void gru2_kernel(const float* __restrict__ x,
                 const float* __restrict__ Wih0, const float* __restrict__ Whh0,
                 const float* __restrict__ bih0, const float* __restrict__ bhh0,
                 const float* __restrict__ Wih1, const float* __restrict__ Whh1,
                 const float* __restrict__ bih1, const float* __restrict__ bhh1,
                 float* __restrict__ out)
{
    __shared__ __align__(16) float Lx[EPB][ISZ];        // x_t staging
    __shared__ __align__(16) float H0s[EPB][HID];       // layer-0 h
    __shared__ __align__(16) float H1s[EPB][HID];       // layer-1 h
    __shared__ __align__(16) float G[2][2][EPB][120];   // [layer][part][e][row]

    const int tid    = threadIdx.x;
    const int stripe = tid >> 7;          // 0..3 (wave-aligned role)
    const int lane_s = tid & 127;
    const bool dotlane = lane_s < 120;
    const int row  = dotlane ? lane_s : 0;
    const int lyr  = stripe >> 1;         // 0,0,1,1
    const int part = stripe & 1;          // 0=input-proj, 1=hidden-proj
    const int e0   = blockIdx.x * EPB;

    // ---- per-lane weights (<=10 float4) + bias into registers ----
    const float* Wsel;
    const float* bsel;
    if (stripe == 0)      { Wsel = Wih0 + row * ISZ; bsel = bih0; }
    else if (stripe == 1) { Wsel = Whh0 + row * HID; bsel = bhh0; }
    else if (stripe == 2) { Wsel = Wih1 + row * HID; bsel = bih1; }
    else                  { Wsel = Whh1 + row * HID; bsel = bhh1; }

    float4 w[10];
    if (stripe == 0) {
        #pragma unroll
        for (int k = 0; k < 4; ++k) w[k] = ((const float4*)Wsel)[k];
        #pragma unroll
        for (int k = 4; k < 10; ++k) w[k] = make_float4(0.f, 0.f, 0.f, 0.f);
    } else {
        #pragma unroll
        for (int k = 0; k < 10; ++k) w[k] = ((const float4*)Wsel)[k];
    }
    const float bias = bsel[row];

    // ---- init h states, stage x[0] ----
    if (tid < EPB * HID) {
        ((float*)H0s)[tid] = 0.0f;
        ((float*)H1s)[tid] = 0.0f;
    }
    if (tid < EPB * ISZ) {
        const int e = tid >> 4, k = tid & 15;
        Lx[e][k] = x[(size_t)(e0 + e) * (T_STEPS * ISZ) + k];
    }
    __syncthreads();

    for (int t = 0; t <= T_STEPS; ++t) {
        // ---- dot phase: all projection lanes compute their 8 partial rows ----
        if (dotlane) {
            float acc[EPB];
            if (stripe == 0) {
                #pragma unroll
                for (int e = 0; e < EPB; ++e) {
                    const float4* sv = (const float4*)Lx[e];   // wave-broadcast
                    float s = bias;
                    #pragma unroll
                    for (int k = 0; k < 4; ++k) {
                        float4 v = sv[k];
                        s += w[k].x*v.x + w[k].y*v.y + w[k].z*v.z + w[k].w*v.w;
                    }
                    acc[e] = s;
                }
            } else {
                const float (*Sp)[HID] = (stripe == 3) ? H1s : H0s;
                #pragma unroll
                for (int e = 0; e < EPB; ++e) {
                    const float4* sv = (const float4*)Sp[e];   // wave-broadcast
                    float s = bias;
                    #pragma unroll
                    for (int k = 0; k < 10; ++k) {
                        float4 v = sv[k];
                        s += w[k].x*v.x + w[k].y*v.y + w[k].z*v.z + w[k].w*v.w;
                    }
                    acc[e] = s;
                }
            }
            #pragma unroll
            for (int e = 0; e < EPB; ++e) G[lyr][part][e][row] = acc[e];
        }
        __syncthreads();

        // ---- stage x[t+1] for next iteration's dot phase ----
        if (t < T_STEPS - 1 && tid < EPB * ISZ) {
            const int e = tid >> 4, k = tid & 15;
            Lx[e][k] = x[(size_t)(e0 + e) * (T_STEPS * ISZ) + (t + 1) * ISZ + k];
        }

        // ---- assembly: 640 tasks (layer, elem, unit) over 512 lanes ----
        for (int task = tid; task < 2 * EPB * HID; task += NTHR) {
            const int i    = task % HID;
            const int rest = task / HID;     // 0..15
            const int e    = rest & 7;
            const int ll   = rest >> 3;      // layer (wave-uniform: boundary at task 320)
            // L0 valid for t<256 (produces h0[t]); L1 valid for t>0 (produces h1[t-1])
            const bool doit = (ll == 0) ? (t < T_STEPS) : (t > 0);
            if (doit) {
                const float r = sigm(G[ll][0][e][i]           + G[ll][1][e][i]);
                const float z = sigm(G[ll][0][e][HID + i]     + G[ll][1][e][HID + i]);
                const float n = tanh_f(G[ll][0][e][2*HID + i] + r * G[ll][1][e][2*HID + i]);
                if (ll == 0) {
                    const float h = H0s[e][i];
                    H0s[e][i] = (1.0f - z) * n + z * h;
                } else {
                    const float h = H1s[e][i];
                    H1s[e][i] = (1.0f - z) * n + z * h;
                }
            }
        }
        __syncthreads();
    }

    // ---- write h1[255]: layout [e][i] flat == out[(e0+e)*40+i] ----
    if (tid < EPB * HID) {
        out[(size_t)e0 * HID + tid] = ((float*)H1s)[tid];
    }
}

extern "C" void kernel_launch(void* const* d_in, const int* in_sizes, int n_in,
                              void* d_out, int out_size, void* d_ws, size_t ws_size,
                              hipStream_t stream) {
    const float* x    = (const float*)d_in[0];
    const float* Wih0 = (const float*)d_in[1];
    const float* Whh0 = (const float*)d_in[2];
    const float* bih0 = (const float*)d_in[3];
    const float* bhh0 = (const float*)d_in[4];
    const float* Wih1 = (const float*)d_in[5];
    const float* Whh1 = (const float*)d_in[6];
    const float* bih1 = (const float*)d_in[7];
    const float* bhh1 = (const float*)d_in[8];
    float* out = (float*)d_out;

    dim3 grid(4096 / EPB), block(NTHR);
    hipLaunchKernelGGL(gru2_kernel, grid, block, 0, stream,
                       x, Wih0, Whh0, bih0, bhh0, Wih1, Whh1, bih1, bhh1, out);
}

// Round 4
// 1517.317 us; speedup vs baseline: 3.7858x; 3.7858x over previous
//
#include <hip/hip_runtime.h>

#define T_STEPS 256
#define ISZ 16
#define HID 40
#define EPB 8            // batch elems per block
#define NTHR 512

__device__ __forceinline__ float sigm(float v)  { return 1.0f / (1.0f + __expf(-v)); }
__device__ __forceinline__ float tanh_f(float v){ return 1.0f - 2.0f / (__expf(2.0f * v) + 1.0f); }

// Named members, NOT an array: rounds 1-3 showed the compiler demotes indexed
// local arrays to scratch (r3: w[10] -> 16 GB spill traffic, VGPR capped 64).
struct W40 { float4 a, b, c, d, e, f, g, h, i, j; };

__device__ __forceinline__ float dot40(const float* __restrict__ p, const W40& w, float bias) {
    const float4* v = (const float4*)p;   // wave-uniform LDS broadcast reads
    float4 v0 = v[0], v1 = v[1], v2 = v[2], v3 = v[3], v4 = v[4];
    float4 v5 = v[5], v6 = v[6], v7 = v[7], v8 = v[8], v9 = v[9];
    float s = bias;
    s += w.a.x*v0.x + w.a.y*v0.y + w.a.z*v0.z + w.a.w*v0.w;
    s += w.b.x*v1.x + w.b.y*v1.y + w.b.z*v1.z + w.b.w*v1.w;
    s += w.c.x*v2.x + w.c.y*v2.y + w.c.z*v2.z + w.c.w*v2.w;
    s += w.d.x*v3.x + w.d.y*v3.y + w.d.z*v3.z + w.d.w*v3.w;
    s += w.e.x*v4.x + w.e.y*v4.y + w.e.z*v4.z + w.e.w*v4.w;
    s += w.f.x*v5.x + w.f.y*v5.y + w.f.z*v5.z + w.f.w*v5.w;
    s += w.g.x*v6.x + w.g.y*v6.y + w.g.z*v6.z + w.g.w*v6.w;
    s += w.h.x*v7.x + w.h.y*v7.y + w.h.z*v7.z + w.h.w*v7.w;
    s += w.i.x*v8.x + w.i.y*v8.y + w.i.z*v8.z + w.i.w*v8.w;
    s += w.j.x*v9.x + w.j.y*v9.y + w.j.z*v9.z + w.j.w*v9.w;
    return s;
}

// 4 stripes of 128 lanes, lanes 0-119 own one gate-row projection part:
//   stripe 0: L0 input-proj (reads Lx, padded to 40 w/ zeros)
//   stripe 1: L0 hidden-proj (reads H0s)   stripe 2: L1 input-proj (reads H0s)
//   stripe 3: L1 hidden-proj (reads H1s)
// Layer skew: iter t computes h0[t] and h1[t-1]; 2 barriers/step.
__global__ __launch_bounds__(NTHR, 2)
void gru2_kernel(const float* __restrict__ x,
                 const float* __restrict__ Wih0, const float* __restrict__ Whh0,
                 const float* __restrict__ bih0, const float* __restrict__ bhh0,
                 const float* __restrict__ Wih1, const float* __restrict__ Whh1,
                 const float* __restrict__ bih1, const float* __restrict__ bhh1,
                 float* __restrict__ out)
{
    __shared__ __align__(16) float Lx[EPB][HID];        // x_t staging, k>=16 stays 0
    __shared__ __align__(16) float H0s[EPB][HID];
    __shared__ __align__(16) float H1s[EPB][HID];
    __shared__ __align__(16) float G[2][2][EPB][120];   // [layer][part][e][row]

    const int tid    = threadIdx.x;
    const int stripe = tid >> 7;
    const int lane_s = tid & 127;
    const bool dotlane = lane_s < 120;
    const int row  = dotlane ? lane_s : 0;
    const int lyr  = stripe >> 1;
    const int part = stripe & 1;
    const int e0   = blockIdx.x * EPB;

    const float* Wsel; const float* bsel;
    if (stripe == 0)      { Wsel = Wih0 + row * ISZ; bsel = bih0; }
    else if (stripe == 1) { Wsel = Whh0 + row * HID; bsel = bhh0; }
    else if (stripe == 2) { Wsel = Wih1 + row * HID; bsel = bih1; }
    else                  { Wsel = Whh1 + row * HID; bsel = bhh1; }

    const float4* Wp = (const float4*)Wsel;
    W40 w;
    w.a = Wp[0]; w.b = Wp[1]; w.c = Wp[2]; w.d = Wp[3];
    if (stripe == 0) {
        w.e = w.f = w.g = w.h = w.i = w.j = make_float4(0.f, 0.f, 0.f, 0.f);
    } else {
        w.e = Wp[4]; w.f = Wp[5]; w.g = Wp[6]; w.h = Wp[7]; w.i = Wp[8]; w.j = Wp[9];
    }
    const float bias = bsel[row];

    // init: zero h-states AND all of Lx (its k>=16 tail must be 0 forever)
    if (tid < EPB * HID) {
        ((float*)H0s)[tid] = 0.0f;
        ((float*)H1s)[tid] = 0.0f;
        ((float*)Lx)[tid]  = 0.0f;
    }
    __syncthreads();
    if (tid < EPB * ISZ) {
        const int e = tid >> 4, k = tid & 15;
        Lx[e][k] = x[(size_t)(e0 + e) * (T_STEPS * ISZ) + k];
    }
    __syncthreads();

    for (int t = 0; t <= T_STEPS; ++t) {
        // ---- dot phase: uniform across stripes ----
        if (dotlane) {
            const float (*Sp)[HID] = (stripe == 0) ? Lx : (stripe == 3) ? H1s : H0s;
            float a0 = dot40(Sp[0], w, bias);
            float a1 = dot40(Sp[1], w, bias);
            float a2 = dot40(Sp[2], w, bias);
            float a3 = dot40(Sp[3], w, bias);
            float a4 = dot40(Sp[4], w, bias);
            float a5 = dot40(Sp[5], w, bias);
            float a6 = dot40(Sp[6], w, bias);
            float a7 = dot40(Sp[7], w, bias);
            float* g = &G[lyr][part][0][row];      // elem stride = 120 floats
            g[0]   = a0; g[120] = a1; g[240] = a2; g[360] = a3;
            g[480] = a4; g[600] = a5; g[720] = a6; g[840] = a7;
        }
        __syncthreads();

        // ---- stage x[t+1] ----
        if (t < T_STEPS - 1 && tid < EPB * ISZ) {
            const int e = tid >> 4, k = tid & 15;
            Lx[e][k] = x[(size_t)(e0 + e) * (T_STEPS * ISZ) + (t + 1) * ISZ + k];
        }

        // ---- assembly: 640 tasks (layer, elem, unit) ----
        for (int task = tid; task < 2 * EPB * HID; task += NTHR) {
            const int i    = task % HID;
            const int rest = task / HID;
            const int e    = rest & 7;
            const int ll   = rest >> 3;
            const bool doit = (ll == 0) ? (t < T_STEPS) : (t > 0);
            if (doit) {
                const float r = sigm(G[ll][0][e][i]           + G[ll][1][e][i]);
                const float z = sigm(G[ll][0][e][HID + i]     + G[ll][1][e][HID + i]);
                const float n = tanh_f(G[ll][0][e][2*HID + i] + r * G[ll][1][e][2*HID + i]);
                if (ll == 0) {
                    H0s[e][i] = (1.0f - z) * n + z * H0s[e][i];
                } else {
                    H1s[e][i] = (1.0f - z) * n + z * H1s[e][i];
                }
            }
        }
        __syncthreads();
    }

    if (tid < EPB * HID) {
        out[(size_t)e0 * HID + tid] = ((float*)H1s)[tid];
    }
}

extern "C" void kernel_launch(void* const* d_in, const int* in_sizes, int n_in,
                              void* d_out, int out_size, void* d_ws, size_t ws_size,
                              hipStream_t stream) {
    const float* x    = (const float*)d_in[0];
    const float* Wih0 = (const float*)d_in[1];
    const float* Whh0 = (const float*)d_in[2];
    const float* bih0 = (const float*)d_in[3];
    const float* bhh0 = (const float*)d_in[4];
    const float* Wih1 = (const float*)d_in[5];
    const float* Whh1 = (const float*)d_in[6];
    const float* bih1 = (const float*)d_in[7];
    const float* bhh1 = (const float*)d_in[8];
    float* out = (float*)d_out;

    dim3 grid(4096 / EPB), block(NTHR);
    hipLaunchKernelGGL(gru2_kernel, grid, block, 0, stream,
                       x, Wih0, Whh0, bih0, bhh0, Wih1, Whh1, bih1, bhh1, out);
}

// Round 5
// 1483.131 us; speedup vs baseline: 3.8731x; 1.0231x over previous
//
#include <hip/hip_runtime.h>

#define T_STEPS 256
#define ISZ 16
#define HID 40
#define EPB 8            // batch elems per block
#define NTHR 512

__device__ __forceinline__ float sigm(float v)  { return 1.0f / (1.0f + __expf(-v)); }
__device__ __forceinline__ float tanh_f(float v){ return 1.0f - 2.0f / (__expf(2.0f * v) + 1.0f); }

// Named members, NOT an array (r3: indexed local array -> scratch, 16 GB traffic).
struct W40 { float4 a, b, c, d, e, f, g, h, i, j; };

// r4 lesson: even named-scalar weights get REMATERIALIZED (VGPR=48, reloads
// from L2 every step, 1517 us latency-bound). Empty inline asm makes each
// component an opaque SSA value the compiler cannot re-derive -> stays in VGPR.
#define PIN4(q) asm volatile("" : "+v"((q).x), "+v"((q).y), "+v"((q).z), "+v"((q).w))

__device__ __forceinline__ float dot40(const float* __restrict__ p, const W40& w, float bias) {
    const float4* v = (const float4*)p;   // wave-uniform LDS broadcast reads
    float4 v0 = v[0], v1 = v[1], v2 = v[2], v3 = v[3], v4 = v[4];
    float4 v5 = v[5], v6 = v[6], v7 = v[7], v8 = v[8], v9 = v[9];
    float s = bias;
    s += w.a.x*v0.x + w.a.y*v0.y + w.a.z*v0.z + w.a.w*v0.w;
    s += w.b.x*v1.x + w.b.y*v1.y + w.b.z*v1.z + w.b.w*v1.w;
    s += w.c.x*v2.x + w.c.y*v2.y + w.c.z*v2.z + w.c.w*v2.w;
    s += w.d.x*v3.x + w.d.y*v3.y + w.d.z*v3.z + w.d.w*v3.w;
    s += w.e.x*v4.x + w.e.y*v4.y + w.e.z*v4.z + w.e.w*v4.w;
    s += w.f.x*v5.x + w.f.y*v5.y + w.f.z*v5.z + w.f.w*v5.w;
    s += w.g.x*v6.x + w.g.y*v6.y + w.g.z*v6.z + w.g.w*v6.w;
    s += w.h.x*v7.x + w.h.y*v7.y + w.h.z*v7.z + w.h.w*v7.w;
    s += w.i.x*v8.x + w.i.y*v8.y + w.i.z*v8.z + w.i.w*v8.w;
    s += w.j.x*v9.x + w.j.y*v9.y + w.j.z*v9.z + w.j.w*v9.w;
    return s;
}

// 4 stripes of 128 lanes, lanes 0-119 own one gate-row projection part:
//   stripe 0: L0 input-proj (reads Lx, padded to 40 w/ zeros)
//   stripe 1: L0 hidden-proj (reads H0s)   stripe 2: L1 input-proj (reads H0s)
//   stripe 3: L1 hidden-proj (reads H1s)
// Layer skew: iter t computes h0[t] and h1[t-1]; 2 barriers/step.
// launch_bounds(512,4): cap VGPR at 128 so 2 blocks/CU (16 waves) stay resident.
__global__ __launch_bounds__(NTHR, 4)
void gru2_kernel(const float* __restrict__ x,
                 const float* __restrict__ Wih0, const float* __restrict__ Whh0,
                 const float* __restrict__ bih0, const float* __restrict__ bhh0,
                 const float* __restrict__ Wih1, const float* __restrict__ Whh1,
                 const float* __restrict__ bih1, const float* __restrict__ bhh1,
                 float* __restrict__ out)
{
    __shared__ __align__(16) float Lx[EPB][HID];        // x_t staging, k>=16 stays 0
    __shared__ __align__(16) float H0s[EPB][HID];
    __shared__ __align__(16) float H1s[EPB][HID];
    __shared__ __align__(16) float G[2][2][EPB][120];   // [layer][part][e][row]

    const int tid    = threadIdx.x;
    const int stripe = tid >> 7;
    const int lane_s = tid & 127;
    const bool dotlane = lane_s < 120;
    const int row  = dotlane ? lane_s : 0;
    const int lyr  = stripe >> 1;
    const int part = stripe & 1;
    const int e0   = blockIdx.x * EPB;

    const float* Wsel; const float* bsel;
    if (stripe == 0)      { Wsel = Wih0 + row * ISZ; bsel = bih0; }
    else if (stripe == 1) { Wsel = Whh0 + row * HID; bsel = bhh0; }
    else if (stripe == 2) { Wsel = Wih1 + row * HID; bsel = bih1; }
    else                  { Wsel = Whh1 + row * HID; bsel = bhh1; }

    const float4* Wp = (const float4*)Wsel;
    W40 w;
    w.a = Wp[0]; w.b = Wp[1]; w.c = Wp[2]; w.d = Wp[3];
    if (stripe == 0) {
        w.e = w.f = w.g = w.h = w.i = w.j = make_float4(0.f, 0.f, 0.f, 0.f);
    } else {
        w.e = Wp[4]; w.f = Wp[5]; w.g = Wp[6]; w.h = Wp[7]; w.i = Wp[8]; w.j = Wp[9];
    }
    const float bias = bsel[row];

    // Pin all 40 weight floats into VGPRs for the whole t-loop.
    PIN4(w.a); PIN4(w.b); PIN4(w.c); PIN4(w.d); PIN4(w.e);
    PIN4(w.f); PIN4(w.g); PIN4(w.h); PIN4(w.i); PIN4(w.j);

    // init: zero h-states AND all of Lx (its k>=16 tail must be 0 forever)
    if (tid < EPB * HID) {
        ((float*)H0s)[tid] = 0.0f;
        ((float*)H1s)[tid] = 0.0f;
        ((float*)Lx)[tid]  = 0.0f;
    }
    __syncthreads();
    if (tid < EPB * ISZ) {
        const int e = tid >> 4, k = tid & 15;
        Lx[e][k] = x[(size_t)(e0 + e) * (T_STEPS * ISZ) + k];
    }
    __syncthreads();

    for (int t = 0; t <= T_STEPS; ++t) {
        // ---- dot phase: uniform across stripes ----
        if (dotlane) {
            const float (*Sp)[HID] = (stripe == 0) ? Lx : (stripe == 3) ? H1s : H0s;
            float a0 = dot40(Sp[0], w, bias);
            float a1 = dot40(Sp[1], w, bias);
            float a2 = dot40(Sp[2], w, bias);
            float a3 = dot40(Sp[3], w, bias);
            float a4 = dot40(Sp[4], w, bias);
            float a5 = dot40(Sp[5], w, bias);
            float a6 = dot40(Sp[6], w, bias);
            float a7 = dot40(Sp[7], w, bias);
            float* g = &G[lyr][part][0][row];      // elem stride = 120 floats
            g[0]   = a0; g[120] = a1; g[240] = a2; g[360] = a3;
            g[480] = a4; g[600] = a5; g[720] = a6; g[840] = a7;
        }
        __syncthreads();

        // ---- stage x[t+1] ----
        if (t < T_STEPS - 1 && tid < EPB * ISZ) {
            const int e = tid >> 4, k = tid & 15;
            Lx[e][k] = x[(size_t)(e0 + e) * (T_STEPS * ISZ) + (t + 1) * ISZ + k];
        }

        // ---- assembly: 640 tasks (layer, elem, unit) ----
        for (int task = tid; task < 2 * EPB * HID; task += NTHR) {
            const int i    = task % HID;
            const int rest = task / HID;
            const int e    = rest & 7;
            const int ll   = rest >> 3;
            const bool doit = (ll == 0) ? (t < T_STEPS) : (t > 0);
            if (doit) {
                const float r = sigm(G[ll][0][e][i]           + G[ll][1][e][i]);
                const float z = sigm(G[ll][0][e][HID + i]     + G[ll][1][e][HID + i]);
                const float n = tanh_f(G[ll][0][e][2*HID + i] + r * G[ll][1][e][2*HID + i]);
                if (ll == 0) {
                    H0s[e][i] = (1.0f - z) * n + z * H0s[e][i];
                } else {
                    H1s[e][i] = (1.0f - z) * n + z * H1s[e][i];
                }
            }
        }
        __syncthreads();
    }

    if (tid < EPB * HID) {
        out[(size_t)e0 * HID + tid] = ((float*)H1s)[tid];
    }
}

extern "C" void kernel_launch(void* const* d_in, const int* in_sizes, int n_in,
                              void* d_out, int out_size, void* d_ws, size_t ws_size,
                              hipStream_t stream) {
    const float* x    = (const float*)d_in[0];
    const float* Wih0 = (const float*)d_in[1];
    const float* Whh0 = (const float*)d_in[2];
    const float* bih0 = (const float*)d_in[3];
    const float* bhh0 = (const float*)d_in[4];
    const float* Wih1 = (const float*)d_in[5];
    const float* Whh1 = (const float*)d_in[6];
    const float* bih1 = (const float*)d_in[7];
    const float* bhh1 = (const float*)d_in[8];
    float* out = (float*)d_out;

    dim3 grid(4096 / EPB), block(NTHR);
    hipLaunchKernelGGL(gru2_kernel, grid, block, 0, stream,
                       x, Wih0, Whh0, bih0, bhh0, Wih1, Whh1, bih1, bhh1, out);
}

// Round 6
// 983.638 us; speedup vs baseline: 5.8398x; 1.5078x over previous
//
#include <hip/hip_runtime.h>

#define T_STEPS 256
#define ISZ 16
#define HID 40
#define EPB 8            // batch elems per block
#define NTHR 256

__device__ __forceinline__ float sigm(float v)  { return 1.0f / (1.0f + __expf(-v)); }
__device__ __forceinline__ float tanh_f(float v){ return 1.0f - 2.0f / (__expf(2.0f * v) + 1.0f); }

// r5 lesson: inline-asm pin is REQUIRED to keep weights in VGPRs (without it
// the compiler rematerializes loads every step; with it VGPR=52 and weights
// stayed resident). r5's real bottleneck: wave-uniform ds_read_b128 costs the
// full LDS return bandwidth (~8 cyc) but fed only 4 FMAs at R=1 row/lane ->
// LDS pipe 4x oversubscribed (10240 cyc/CU/step vs 2500 VALU). This kernel:
// R=4 rows/lane sharing one state operand -> 16 FMA per broadcast read.
#define PIN4(q) asm volatile("" : "+v"((q).x), "+v"((q).y), "+v"((q).z), "+v"((q).w))

// Roles (wave-uniform):
//  A: rows {l, l+60} of Whh0 AND Wih1 -- all four dots read H0s (h0[t-1])
//  B: rows {l, l+60} of Whh1 (reads H1s) + Wih0 (reads Lx)
// Weight STORAGE is unified (same named float4s in both roles) so the register
// allocator sees one 160-float set, not two.
__global__ __launch_bounds__(NTHR, 2)
void gru2_kernel(const float* __restrict__ x,
                 const float* __restrict__ Wih0, const float* __restrict__ Whh0,
                 const float* __restrict__ bih0, const float* __restrict__ bhh0,
                 const float* __restrict__ Wih1, const float* __restrict__ Whh1,
                 const float* __restrict__ bih1, const float* __restrict__ bhh1,
                 float* __restrict__ out)
{
    __shared__ __align__(16) float Lx[EPB][ISZ];
    __shared__ __align__(16) float H0s[EPB][HID];
    __shared__ __align__(16) float H1s[EPB][HID];
    __shared__ __align__(16) float G[2][2][EPB][120];   // [layer][part][e][row]

    const int tid  = threadIdx.x;
    const int wid  = tid >> 6;          // wave 0..3
    const int lane = tid & 63;
    const bool act = lane < 60;
    const int l    = act ? lane : 59;   // clamped row base
    const int r0   = l, r1 = l + 60;
    // Alternate role with block parity so each SIMD hosts one A and one B wave
    // from the two co-resident blocks.
    const bool roleA = (((wid + (int)blockIdx.x) & 1) == 0);
    const int eb   = (wid >> 1) << 2;   // elem half: 0 or 4
    const int e0   = blockIdx.x * EPB;

#define DECLW(n) float4 w0_##n, w1_##n, w2_##n, w3_##n
    DECLW(0); DECLW(1); DECLW(2); DECLW(3); DECLW(4);
    DECLW(5); DECLW(6); DECLW(7); DECLW(8); DECLW(9);
    float b0, b1, b2, b3;

    {
        const float4 z4 = make_float4(0.f, 0.f, 0.f, 0.f);
        if (roleA) {
            const float4* p0 = (const float4*)(Whh0 + r0 * HID);
            const float4* p1 = (const float4*)(Whh0 + r1 * HID);
            const float4* p2 = (const float4*)(Wih1 + r0 * HID);
            const float4* p3 = (const float4*)(Wih1 + r1 * HID);
#define LDA(n) w0_##n = p0[n]; w1_##n = p1[n]; w2_##n = p2[n]; w3_##n = p3[n]
            LDA(0); LDA(1); LDA(2); LDA(3); LDA(4);
            LDA(5); LDA(6); LDA(7); LDA(8); LDA(9);
            b0 = bhh0[r0]; b1 = bhh0[r1]; b2 = bih1[r0]; b3 = bih1[r1];
        } else {
            const float4* p0 = (const float4*)(Whh1 + r0 * HID);
            const float4* p1 = (const float4*)(Whh1 + r1 * HID);
            const float4* p2 = (const float4*)(Wih0 + r0 * ISZ);
            const float4* p3 = (const float4*)(Wih0 + r1 * ISZ);
#define LDB(n) w0_##n = p0[n]; w1_##n = p1[n]
            LDB(0); LDB(1); LDB(2); LDB(3); LDB(4);
            LDB(5); LDB(6); LDB(7); LDB(8); LDB(9);
            w2_0 = p2[0]; w2_1 = p2[1]; w2_2 = p2[2]; w2_3 = p2[3];
            w3_0 = p3[0]; w3_1 = p3[1]; w3_2 = p3[2]; w3_3 = p3[3];
            w2_4 = z4; w2_5 = z4; w2_6 = z4; w2_7 = z4; w2_8 = z4; w2_9 = z4;
            w3_4 = z4; w3_5 = z4; w3_6 = z4; w3_7 = z4; w3_8 = z4; w3_9 = z4;
            b0 = bhh1[r0]; b1 = bhh1[r1]; b2 = bih0[r0]; b3 = bih0[r1];
        }
    }
#define PINW(n) PIN4(w0_##n); PIN4(w1_##n); PIN4(w2_##n); PIN4(w3_##n)
    PINW(0); PINW(1); PINW(2); PINW(3); PINW(4);
    PINW(5); PINW(6); PINW(7); PINW(8); PINW(9);
    asm volatile("" : "+v"(b0), "+v"(b1), "+v"(b2), "+v"(b3));

    // init states, stage x[0]
    for (int idx = tid; idx < EPB * HID; idx += NTHR) {
        ((float*)H0s)[idx] = 0.0f;
        ((float*)H1s)[idx] = 0.0f;
    }
    if (tid < EPB * ISZ) {
        const int e = tid >> 4, k = tid & 15;
        Lx[e][k] = x[(size_t)(e0 + e) * (T_STEPS * ISZ) + k];
    }
    __syncthreads();

#define DOTQ(n, v) \
    ax += w0_##n.x*(v).x + w0_##n.y*(v).y + w0_##n.z*(v).z + w0_##n.w*(v).w; \
    ay += w1_##n.x*(v).x + w1_##n.y*(v).y + w1_##n.z*(v).z + w1_##n.w*(v).w;
#define DOTQ2(n, v) \
    az += w2_##n.x*(v).x + w2_##n.y*(v).y + w2_##n.z*(v).z + w2_##n.w*(v).w; \
    aw += w3_##n.x*(v).x + w3_##n.y*(v).y + w3_##n.z*(v).z + w3_##n.w*(v).w;

    for (int t = 0; t <= T_STEPS; ++t) {
        // ---- dot phase ----
        if (roleA) {
            #pragma unroll
            for (int e = 0; e < 4; ++e) {
                const float4* S = (const float4*)H0s[eb + e];
                float ax = b0, ay = b1, az = b2, aw = b3;
                { float4 v = S[0]; DOTQ(0, v) DOTQ2(0, v) }
                { float4 v = S[1]; DOTQ(1, v) DOTQ2(1, v) }
                { float4 v = S[2]; DOTQ(2, v) DOTQ2(2, v) }
                { float4 v = S[3]; DOTQ(3, v) DOTQ2(3, v) }
                { float4 v = S[4]; DOTQ(4, v) DOTQ2(4, v) }
                { float4 v = S[5]; DOTQ(5, v) DOTQ2(5, v) }
                { float4 v = S[6]; DOTQ(6, v) DOTQ2(6, v) }
                { float4 v = S[7]; DOTQ(7, v) DOTQ2(7, v) }
                { float4 v = S[8]; DOTQ(8, v) DOTQ2(8, v) }
                { float4 v = S[9]; DOTQ(9, v) DOTQ2(9, v) }
                if (act) {
                    G[0][1][eb + e][r0] = ax;   // Whh0 row r0  (L0 hidden)
                    G[0][1][eb + e][r1] = ay;
                    G[1][0][eb + e][r0] = az;   // Wih1 row r0  (L1 input)
                    G[1][0][eb + e][r1] = aw;
                }
            }
        } else {
            #pragma unroll
            for (int e = 0; e < 4; ++e) {
                const float4* S = (const float4*)H1s[eb + e];
                const float4* X = (const float4*)Lx[eb + e];
                float ax = b0, ay = b1, az = b2, aw = b3;
                { float4 v = S[0]; DOTQ(0, v) }
                { float4 v = S[1]; DOTQ(1, v) }
                { float4 v = S[2]; DOTQ(2, v) }
                { float4 v = S[3]; DOTQ(3, v) }
                { float4 v = S[4]; DOTQ(4, v) }
                { float4 v = S[5]; DOTQ(5, v) }
                { float4 v = S[6]; DOTQ(6, v) }
                { float4 v = S[7]; DOTQ(7, v) }
                { float4 v = S[8]; DOTQ(8, v) }
                { float4 v = S[9]; DOTQ(9, v) }
                { float4 u = X[0]; DOTQ2(0, u) }
                { float4 u = X[1]; DOTQ2(1, u) }
                { float4 u = X[2]; DOTQ2(2, u) }
                { float4 u = X[3]; DOTQ2(3, u) }
                if (act) {
                    G[1][1][eb + e][r0] = ax;   // Whh1 row r0  (L1 hidden)
                    G[1][1][eb + e][r1] = ay;
                    G[0][0][eb + e][r0] = az;   // Wih0 row r0  (L0 input)
                    G[0][0][eb + e][r1] = aw;
                }
            }
        }
        __syncthreads();

        // ---- stage x[t+1] ----
        if (t < T_STEPS - 1 && tid < EPB * ISZ) {
            const int e = tid >> 4, k = tid & 15;
            Lx[e][k] = x[(size_t)(e0 + e) * (T_STEPS * ISZ) + (t + 1) * ISZ + k];
        }

        // ---- assembly: 640 tasks (layer, elem, unit) ----
        for (int task = tid; task < 2 * EPB * HID; task += NTHR) {
            const int i    = task % HID;
            const int rest = task / HID;
            const int e    = rest & 7;
            const int ll   = rest >> 3;
            const bool doit = (ll == 0) ? (t < T_STEPS) : (t > 0);
            if (doit) {
                const float r = sigm(G[ll][0][e][i]           + G[ll][1][e][i]);
                const float z = sigm(G[ll][0][e][HID + i]     + G[ll][1][e][HID + i]);
                const float n = tanh_f(G[ll][0][e][2*HID + i] + r * G[ll][1][e][2*HID + i]);
                if (ll == 0) {
                    H0s[e][i] = (1.0f - z) * n + z * H0s[e][i];
                } else {
                    H1s[e][i] = (1.0f - z) * n + z * H1s[e][i];
                }
            }
        }
        __syncthreads();
    }

    for (int idx = tid; idx < EPB * HID; idx += NTHR) {
        out[(size_t)e0 * HID + idx] = ((float*)H1s)[idx];
    }
}

extern "C" void kernel_launch(void* const* d_in, const int* in_sizes, int n_in,
                              void* d_out, int out_size, void* d_ws, size_t ws_size,
                              hipStream_t stream) {
    const float* x    = (const float*)d_in[0];
    const float* Wih0 = (const float*)d_in[1];
    const float* Whh0 = (const float*)d_in[2];
    const float* bih0 = (const float*)d_in[3];
    const float* bhh0 = (const float*)d_in[4];
    const float* Wih1 = (const float*)d_in[5];
    const float* Whh1 = (const float*)d_in[6];
    const float* bih1 = (const float*)d_in[7];
    const float* bhh1 = (const float*)d_in[8];
    float* out = (float*)d_out;

    dim3 grid(4096 / EPB), block(NTHR);
    hipLaunchKernelGGL(gru2_kernel, grid, block, 0, stream,
                       x, Wih0, Whh0, bih0, bhh0, Wih1, Whh1, bih1, bhh1, out);
}

// Round 7
// 486.772 us; speedup vs baseline: 11.8008x; 2.0207x over previous
//
#include <hip/hip_runtime.h>

#define T_STEPS 256
#define HID 40
#define EPB 16
#define NTHR 512
#define GSTR 498   // G row stride (floats); 4*GSTR % 32 == 8 -> write quarters hit disjoint banks

typedef __attribute__((ext_vector_type(8))) short bf16x8;
typedef __attribute__((ext_vector_type(4))) float f32x4;

__device__ __forceinline__ unsigned short bf16_rne(float v) {
    unsigned int x = __float_as_uint(v);
    unsigned int r = x + 0x7FFFu + ((x >> 16) & 1u);
    return (unsigned short)(r >> 16);
}
__device__ __forceinline__ float bf16f(unsigned short h) {
    return __uint_as_float(((unsigned int)h) << 16);
}
__device__ __forceinline__ float sigm(float v)  { return 1.0f / (1.0f + __expf(-v)); }
__device__ __forceinline__ float tanh_f(float v){ return 1.0f - 2.0f / (__expf(2.0f * v) + 1.0f); }

#define MF(a, b, c) c = __builtin_amdgcn_mfma_f32_16x16x32_bf16(a, b, c, 0, 0, 0)
#define PINV(v) asm volatile("" : "+v"(v))

// Tile id -> (gemm, nb). gemm0: A=h0-concat, N-space 0..239 (Whh0 rows 0-119 =
// L0-hidden; Wih1 rows = L1-input). gemm1: A=h1-concat, Whh1 (L1-hidden),
// N pad 128. gemm2: A=x-concat (K'=48 pad 64), Wih0 (L0-input), N pad 128.
__device__ __forceinline__ void tile_map(int id, int& g, int& nb) {
    if (id < 15)      { g = 0; nb = id * 16; }
    else if (id < 23) { g = 1; nb = (id - 15) * 16; }
    else              { g = 2; nb = (id - 23) * 16; }
}

// B-fragment: lane holds W'[n = nb+col][k' = q*32 + qrow*8 + j], j=0..7, where
// W' = [wh | wh | wl] along k' (3-term split vs A = [hi | lo | hi]).
__device__ bf16x8 build_frag(int id, int q, int col, int qrow,
                             const float* Wih0, const float* Whh0,
                             const float* Wih1, const float* Whh1) {
    bf16x8 f;
    #pragma unroll
    for (int j = 0; j < 8; ++j) f[j] = 0;
    if (id > 30) return f;
    int g, nb; tile_map(id, g, nb);
    const int n = nb + col;
    const float* Wrow; int K;
    if (g == 0)      { Wrow = (n < 120) ? Whh0 + n * 40 : Wih1 + (n - 120) * 40; K = 40; }
    else if (g == 1) { int nr = n < 120 ? n : 119; Wrow = Whh1 + nr * 40; K = 40; }
    else             { int nr = n < 120 ? n : 119; Wrow = Wih0 + nr * 16; K = 16; }
    #pragma unroll
    for (int j = 0; j < 8; ++j) {
        const int kp = q * 32 + qrow * 8 + j;
        unsigned short bits = 0;
        if (kp < 3 * K) {
            const int seg = kp / K;
            const int k   = kp - seg * K;
            const float wv = Wrow[k];
            const unsigned short whi = bf16_rne(wv);
            bits = (seg < 2) ? whi : bf16_rne(wv - bf16f(whi));
        }
        f[j] = (short)bits;
    }
    return f;
}

// Bias folded into C-init of the INPUT-part tiles (r,z rows: bih+bhh; n rows:
// bih only) and HIDDEN-part n rows (bhh). Assembly then needs no bias reads.
__device__ float bias_for(int id, int col,
                          const float* bih0, const float* bhh0,
                          const float* bih1, const float* bhh1) {
    if (id > 30) return 0.f;
    int g, nb; tile_map(id, g, nb);
    const int n = nb + col;
    if (g == 0) {
        if (n < 120) return (n >= 80) ? bhh0[n] : 0.f;              // L0 hidden-part
        const int i = n - 120;                                       // L1 input-part
        return (i < 80) ? bih1[i] + bhh1[i] : bih1[i];
    } else if (g == 1) {
        return (n < 120 && n >= 80) ? bhh1[n] : 0.f;                // L1 hidden-part
    } else {
        if (n >= 120) return 0.f;                                    // L0 input-part
        return (n < 80) ? bih0[n] + bhh0[n] : bih0[n];
    }
}

__global__ __launch_bounds__(NTHR, 2)
void gru2_kernel(const float* __restrict__ x,
                 const float* __restrict__ Wih0, const float* __restrict__ Whh0,
                 const float* __restrict__ bih0, const float* __restrict__ bhh0,
                 const float* __restrict__ Wih1, const float* __restrict__ Whh1,
                 const float* __restrict__ bih1, const float* __restrict__ bhh1,
                 float* __restrict__ out)
{
    // A-buffers: bf16 K-concat [hi(0:K)|lo(K:2K)|hi(2K:3K)|pad], row stride
    // padded so lane addresses stay 16B-aligned and banks spread like stride-1.
    __shared__ __align__(16) unsigned short A0[EPB][136];  // h0, K'=120 pad 128
    __shared__ __align__(16) unsigned short A1[EPB][136];  // h1
    __shared__ __align__(16) unsigned short Ax[EPB][72];   // x,  K'=48  pad 64
    __shared__ float G[EPB][GSTR];   // pre-activations [m][n-space 0..495]
    __shared__ float H0[EPB][HID];   // fp32 h-states
    __shared__ float H1[EPB][HID];

    const int tid  = threadIdx.x;
    const int wid  = tid >> 6;        // wave 0..7
    const int l    = tid & 63;
    const int col  = l & 15;          // MFMA n/m-col index
    const int qrow = l >> 4;          // quarter-wave
    const int e0   = blockIdx.x * EPB;

    // ---- one-time: B-fragments (weights) into pinned VGPRs ----
    // wave w owns tiles {w, w+8, w+16, w+24}; slot3 invalid for wave 7.
    bf16x8 B00 = build_frag(wid + 0,  0, col, qrow, Wih0, Whh0, Wih1, Whh1);
    bf16x8 B01 = build_frag(wid + 0,  1, col, qrow, Wih0, Whh0, Wih1, Whh1);
    bf16x8 B02 = build_frag(wid + 0,  2, col, qrow, Wih0, Whh0, Wih1, Whh1);
    bf16x8 B03 = build_frag(wid + 0,  3, col, qrow, Wih0, Whh0, Wih1, Whh1);
    bf16x8 B10 = build_frag(wid + 8,  0, col, qrow, Wih0, Whh0, Wih1, Whh1);
    bf16x8 B11 = build_frag(wid + 8,  1, col, qrow, Wih0, Whh0, Wih1, Whh1);
    bf16x8 B12 = build_frag(wid + 8,  2, col, qrow, Wih0, Whh0, Wih1, Whh1);
    bf16x8 B13 = build_frag(wid + 8,  3, col, qrow, Wih0, Whh0, Wih1, Whh1);
    bf16x8 B20 = build_frag(wid + 16, 0, col, qrow, Wih0, Whh0, Wih1, Whh1);
    bf16x8 B21 = build_frag(wid + 16, 1, col, qrow, Wih0, Whh0, Wih1, Whh1);
    bf16x8 B22 = build_frag(wid + 16, 2, col, qrow, Wih0, Whh0, Wih1, Whh1);
    bf16x8 B23 = build_frag(wid + 16, 3, col, qrow, Wih0, Whh0, Wih1, Whh1);
    bf16x8 B30 = build_frag(wid + 24, 0, col, qrow, Wih0, Whh0, Wih1, Whh1);
    bf16x8 B31 = build_frag(wid + 24, 1, col, qrow, Wih0, Whh0, Wih1, Whh1);
    PINV(B00); PINV(B01); PINV(B02); PINV(B03);
    PINV(B10); PINV(B11); PINV(B12); PINV(B13);
    PINV(B20); PINV(B21); PINV(B22); PINV(B23);
    PINV(B30); PINV(B31);

    float bc0 = bias_for(wid + 0,  col, bih0, bhh0, bih1, bhh1);
    float bc1 = bias_for(wid + 8,  col, bih0, bhh0, bih1, bhh1);
    float bc2 = bias_for(wid + 16, col, bih0, bhh0, bih1, bhh1);
    float bc3 = bias_for(wid + 24, col, bih0, bhh0, bih1, bhh1);

    // G-write base pointers per slot (G[m][n], m = qrow*4 + reg)
    float* gw0; float* gw1; float* gw2; float* gw3;
    {
        int g, nb;
        tile_map(wid + 0, g, nb);
        gw0 = &G[0][0] + (qrow * 4) * GSTR + (g == 0 ? nb : g == 1 ? 240 + nb : 368 + nb) + col;
        tile_map(wid + 8, g, nb);
        gw1 = &G[0][0] + (qrow * 4) * GSTR + (g == 0 ? nb : g == 1 ? 240 + nb : 368 + nb) + col;
        tile_map(wid + 16, g, nb);
        gw2 = &G[0][0] + (qrow * 4) * GSTR + (g == 0 ? nb : g == 1 ? 240 + nb : 368 + nb) + col;
        if (wid < 7) {
            tile_map(wid + 24, g, nb);
            gw3 = &G[0][0] + (qrow * 4) * GSTR + (g == 0 ? nb : g == 1 ? 240 + nb : 368 + nb) + col;
        } else gw3 = &G[0][0];
    }

    // A-frag read pointers (lane-distinct: m = col, k-chunk = qrow)
    const unsigned short* a0p = &A0[0][0] + col * 136 + qrow * 8;
    const unsigned short* a1p = &A1[0][0] + col * 136 + qrow * 8;
    const unsigned short* axp = &Ax[0][0] + col * 72  + qrow * 8;

    // ---- init: zero A-buffers (incl. pads: garbage NaN x B=0 would poison
    // accumulators) and h-states; stage x[0] ----
    for (int idx = tid; idx < EPB * 136; idx += NTHR) { (&A0[0][0])[idx] = 0; (&A1[0][0])[idx] = 0; }
    for (int idx = tid; idx < EPB * 72;  idx += NTHR) (&Ax[0][0])[idx] = 0;
    for (int idx = tid; idx < EPB * HID; idx += NTHR) { (&H0[0][0])[idx] = 0.f; (&H1[0][0])[idx] = 0.f; }
    __syncthreads();
    if (tid < 256) {
        const int e = tid >> 4, k = tid & 15;
        const float v = x[(size_t)(e0 + e) * (T_STEPS * 16) + k];
        const unsigned short hb = bf16_rne(v);
        const unsigned short lb = bf16_rne(v - bf16f(hb));
        Ax[e][k] = hb; Ax[e][16 + k] = lb; Ax[e][32 + k] = hb;
    }
    __syncthreads();

    for (int t = 0; t <= T_STEPS; ++t) {
        // ---- prefetch next x (consumed in assembly phase) ----
        float xv = 0.f;
        if (tid < 256 && t < T_STEPS - 1) {
            const int e = tid >> 4, k = tid & 15;
            xv = x[(size_t)(e0 + e) * (T_STEPS * 16) + (t + 1) * 16 + k];
        }

        // ---- dot phase: MFMA over owned tiles ----
        const bf16x8 a00 = *(const bf16x8*)(a0p);
        const bf16x8 a01 = *(const bf16x8*)(a0p + 32);
        const bf16x8 a02 = *(const bf16x8*)(a0p + 64);
        const bf16x8 a03 = *(const bf16x8*)(a0p + 96);
        const bf16x8 a10 = *(const bf16x8*)(a1p);
        const bf16x8 a11 = *(const bf16x8*)(a1p + 32);
        const bf16x8 a12 = *(const bf16x8*)(a1p + 64);
        const bf16x8 a13 = *(const bf16x8*)(a1p + 96);
        const bf16x8 ax0 = *(const bf16x8*)(axp);
        const bf16x8 ax1 = *(const bf16x8*)(axp + 32);

        f32x4 c;
        // slot 0: ids 0..7 -> gemm0 (A0, K4)
        c = (f32x4){bc0, bc0, bc0, bc0};
        MF(a00, B00, c); MF(a01, B01, c); MF(a02, B02, c); MF(a03, B03, c);
        gw0[0] = c[0]; gw0[GSTR] = c[1]; gw0[2*GSTR] = c[2]; gw0[3*GSTR] = c[3];
        // slot 1: ids 8..15 -> gemm0 (wid<7) or gemm1 (wid==7)
        c = (f32x4){bc1, bc1, bc1, bc1};
        if (wid < 7) { MF(a00, B10, c); MF(a01, B11, c); MF(a02, B12, c); MF(a03, B13, c); }
        else         { MF(a10, B10, c); MF(a11, B11, c); MF(a12, B12, c); MF(a13, B13, c); }
        gw1[0] = c[0]; gw1[GSTR] = c[1]; gw1[2*GSTR] = c[2]; gw1[3*GSTR] = c[3];
        // slot 2: ids 16..23 -> gemm1 (wid<7) or gemm2/x (wid==7, K2)
        c = (f32x4){bc2, bc2, bc2, bc2};
        if (wid < 7) { MF(a10, B20, c); MF(a11, B21, c); MF(a12, B22, c); MF(a13, B23, c); }
        else         { MF(ax0, B20, c); MF(ax1, B21, c); }
        gw2[0] = c[0]; gw2[GSTR] = c[1]; gw2[2*GSTR] = c[2]; gw2[3*GSTR] = c[3];
        // slot 3: ids 24..30 -> gemm2/x (wid<7 only, K2)
        if (wid < 7) {
            c = (f32x4){bc3, bc3, bc3, bc3};
            MF(ax0, B30, c); MF(ax1, B31, c);
            gw3[0] = c[0]; gw3[GSTR] = c[1]; gw3[2*GSTR] = c[2]; gw3[3*GSTR] = c[3];
        }
        __syncthreads();

        // ---- assembly: 1280 tasks (layer, elem, unit) ----
        for (int s = 0; s < 3; ++s) {
            const int task = tid + s * NTHR;
            if (task < 2 * EPB * HID) {
                const int i  = task % HID;
                const int r2 = task / HID;     // 0..31
                const int e  = r2 & 15;
                const int ll = r2 >> 4;        // wave-uniform (640 = 10 waves)
                const bool doit = (ll == 0) ? (t < T_STEPS) : (t > 0);
                if (doit) {
                    // n-space: L0: input@368, hidden@0 | L1: input@120, hidden@240
                    const int bx = ll ? 120 : 368;
                    const int bh = ll ? 240 : 0;
                    const float r  = sigm(G[e][bx + i]      + G[e][bh + i]);
                    const float z  = sigm(G[e][bx + 40 + i] + G[e][bh + 40 + i]);
                    const float n  = tanh_f(G[e][bx + 80 + i] + r * G[e][bh + 80 + i]);
                    const float ho = ll ? H1[e][i] : H0[e][i];
                    const float hn = (1.0f - z) * n + z * ho;
                    const unsigned short hb = bf16_rne(hn);
                    const unsigned short lb = bf16_rne(hn - bf16f(hb));
                    if (ll == 0) {
                        H0[e][i] = hn;
                        A0[e][i] = hb; A0[e][40 + i] = lb; A0[e][80 + i] = hb;
                    } else {
                        H1[e][i] = hn;
                        A1[e][i] = hb; A1[e][40 + i] = lb; A1[e][80 + i] = hb;
                    }
                }
            }
        }
        // ---- stage x[t+1] from prefetched register ----
        if (tid < 256 && t < T_STEPS - 1) {
            const int e = tid >> 4, k = tid & 15;
            const unsigned short hb = bf16_rne(xv);
            const unsigned short lb = bf16_rne(xv - bf16f(hb));
            Ax[e][k] = hb; Ax[e][16 + k] = lb; Ax[e][32 + k] = hb;
        }
        __syncthreads();
    }

    // ---- write h1[255]: H1 flat [e][i] == out[(e0+e)*40 + i] ----
    for (int idx = tid; idx < EPB * HID; idx += NTHR) {
        out[(size_t)e0 * HID + idx] = (&H1[0][0])[idx];
    }
}

extern "C" void kernel_launch(void* const* d_in, const int* in_sizes, int n_in,
                              void* d_out, int out_size, void* d_ws, size_t ws_size,
                              hipStream_t stream) {
    const float* x    = (const float*)d_in[0];
    const float* Wih0 = (const float*)d_in[1];
    const float* Whh0 = (const float*)d_in[2];
    const float* bih0 = (const float*)d_in[3];
    const float* bhh0 = (const float*)d_in[4];
    const float* Wih1 = (const float*)d_in[5];
    const float* Whh1 = (const float*)d_in[6];
    const float* bih1 = (const float*)d_in[7];
    const float* bhh1 = (const float*)d_in[8];
    float* out = (float*)d_out;

    dim3 grid(4096 / EPB), block(NTHR);
    hipLaunchKernelGGL(gru2_kernel, grid, block, 0, stream,
                       x, Wih0, Whh0, bih0, bhh0, Wih1, Whh1, bih1, bhh1, out);
}

// Round 8
// 426.940 us; speedup vs baseline: 13.4546x; 1.1401x over previous
//
#include <hip/hip_runtime.h>

#define T_STEPS 256
#define HID 40
#define EPB 16
#define NTHR 512
#define GSTR 498   // G row stride (floats)

typedef __attribute__((ext_vector_type(8))) short bf16x8;
typedef __attribute__((ext_vector_type(4))) float f32x4;

__device__ __forceinline__ unsigned short bf16_rne(float v) {
    unsigned int x = __float_as_uint(v);
    unsigned int r = x + 0x7FFFu + ((x >> 16) & 1u);
    return (unsigned short)(r >> 16);
}
__device__ __forceinline__ float bf16f(unsigned short h) {
    return __uint_as_float(((unsigned int)h) << 16);
}
__device__ __forceinline__ float sigm(float v)  { return 1.0f / (1.0f + __expf(-v)); }
__device__ __forceinline__ float tanh_f(float v){ return 1.0f - 2.0f / (__expf(2.0f * v) + 1.0f); }

#define MF(a, b, c) c = __builtin_amdgcn_mfma_f32_16x16x32_bf16(a, b, c, 0, 0, 0)
#define PINV(v) asm volatile("" : "+v"(v))

// n-space (verified r7): gemm0 cols 0..239 = [Whh0 rows 0-119 (L0 hidden) |
// Wih1 rows 0-119 (L1 input)]; gemm1 @240 = Whh1 (L1 hidden); gemm2 @368 =
// Wih0 (L0 input). A = [hi|lo|hi] K-concat, B = [wh|wh|wl] (3-term split).
__device__ bf16x8 bfrag(int g, int n, int q, int qrow,
                        const float* Wih0, const float* Whh0,
                        const float* Wih1, const float* Whh1) {
    bf16x8 f;
    #pragma unroll
    for (int j = 0; j < 8; ++j) f[j] = 0;
    const float* Wrow; int K;
    if (g == 0)      { Wrow = (n < 120) ? Whh0 + n * 40 : Wih1 + (n - 120) * 40; K = 40; }
    else if (g == 1) { int nr = n < 120 ? n : 119; Wrow = Whh1 + nr * 40; K = 40; }
    else             { int nr = n < 120 ? n : 119; Wrow = Wih0 + nr * 16; K = 16; }
    #pragma unroll
    for (int j = 0; j < 8; ++j) {
        const int kp = q * 32 + qrow * 8 + j;
        if (kp < 3 * K) {
            const int seg = kp / K;
            const int k   = kp - seg * K;
            const float wv = Wrow[k];
            const unsigned short whi = bf16_rne(wv);
            f[j] = (short)((seg < 2) ? whi : bf16_rne(wv - bf16f(whi)));
        }
    }
    return f;
}

__device__ float biasf(int g, int n,
                       const float* bih0, const float* bhh0,
                       const float* bih1, const float* bhh1) {
    if (g == 0) {
        if (n < 120) return (n >= 80) ? bhh0[n] : 0.f;       // L0 hidden-part
        const int i = n - 120;                                // L1 input-part
        return (i < 80) ? bih1[i] + bhh1[i] : bih1[i];
    } else if (g == 1) {
        return (n < 120 && n >= 80) ? bhh1[n] : 0.f;         // L1 hidden-part
    } else {
        if (n >= 120) return 0.f;                             // L0 input-part
        return (n < 80) ? bih0[n] + bhh0[n] : bih0[n];
    }
}

__global__ __launch_bounds__(NTHR, 2)
void gru2_kernel(const float* __restrict__ x,
                 const float* __restrict__ Wih0, const float* __restrict__ Whh0,
                 const float* __restrict__ bih0, const float* __restrict__ bhh0,
                 const float* __restrict__ Wih1, const float* __restrict__ Whh1,
                 const float* __restrict__ bih1, const float* __restrict__ bhh1,
                 float* __restrict__ out)
{
    __shared__ __align__(16) unsigned short A0[EPB][136];  // h0 bf16 concat
    __shared__ __align__(16) unsigned short A1[EPB][136];  // h1
    __shared__ __align__(16) unsigned short Ax[EPB][72];   // x
    __shared__ float G[EPB][GSTR];

    const int tid  = threadIdx.x;
    const int wid  = tid >> 6;
    const int l    = tid & 63;
    const int col  = l & 15;
    const int qrow = l >> 4;
    const int e0   = blockIdx.x * EPB;
    float* Gf = &G[0][0];
    const int mrow = (qrow * 4) * GSTR;

    // ---- wave-specialized B-fragments (unified named storage, pinned) ----
    bf16x8 Z;
    #pragma unroll
    for (int j = 0; j < 8; ++j) Z[j] = 0;
    bf16x8 F00=Z,F01=Z,F02=Z,F03=Z, F10=Z,F11=Z,F12=Z,F13=Z;
    bf16x8 F20=Z,F21=Z,F22=Z,F23=Z, F30=Z,F31=Z,F32=Z,F33=Z;
    float b0=0,b1=0,b2=0,b3=0,b4=0,b5=0,b6=0,b7=0;
    int   o0=0,o1=0,o2=0,o3=0,o4=0,o5=0,o6=0,o7=0;

#define SETT(S, g_, nb_, noff_) { const int n_ = (nb_) + col; \
    F##S##0 = bfrag(g_, n_, 0, qrow, Wih0, Whh0, Wih1, Whh1); \
    F##S##1 = bfrag(g_, n_, 1, qrow, Wih0, Whh0, Wih1, Whh1); \
    F##S##2 = bfrag(g_, n_, 2, qrow, Wih0, Whh0, Wih1, Whh1); \
    F##S##3 = bfrag(g_, n_, 3, qrow, Wih0, Whh0, Wih1, Whh1); \
    b##S = biasf(g_, n_, bih0, bhh0, bih1, bhh1); \
    o##S = mrow + (noff_) + (nb_) + col; }

    if (wid < 5) {               // gemm0: 15 tiles, 3 per wave; reads A0
        SETT(0, 0, (wid*3+0)*16, 0);
        SETT(1, 0, (wid*3+1)*16, 0);
        SETT(2, 0, (wid*3+2)*16, 0);
    } else if (wid < 7) {        // gemm1: 8 tiles, 4 per wave; reads A1
        const int tb = (wid - 5) * 4;
        SETT(0, 1, (tb+0)*16, 240);
        SETT(1, 1, (tb+1)*16, 240);
        SETT(2, 1, (tb+2)*16, 240);
        SETT(3, 1, (tb+3)*16, 240);
    } else {                     // gemm2: 8 tiles (2 quarters each); reads Ax
#define SETX(Fa, Fb, J, bS, oS) { const int n_ = (J)*16 + col; \
        Fa = bfrag(2, n_, 0, qrow, Wih0, Whh0, Wih1, Whh1); \
        Fb = bfrag(2, n_, 1, qrow, Wih0, Whh0, Wih1, Whh1); \
        bS = biasf(2, n_, bih0, bhh0, bih1, bhh1); \
        oS = mrow + 368 + (J)*16 + col; }
        SETX(F00, F01, 0, b0, o0); SETX(F02, F03, 1, b1, o1);
        SETX(F10, F11, 2, b2, o2); SETX(F12, F13, 3, b3, o3);
        SETX(F20, F21, 4, b4, o4); SETX(F22, F23, 5, b5, o5);
        SETX(F30, F31, 6, b6, o6); SETX(F32, F33, 7, b7, o7);
    }
    PINV(F00); PINV(F01); PINV(F02); PINV(F03);
    PINV(F10); PINV(F11); PINV(F12); PINV(F13);
    PINV(F20); PINV(F21); PINV(F22); PINV(F23);
    PINV(F30); PINV(F31); PINV(F32); PINV(F33);
    asm volatile("" : "+v"(b0), "+v"(b1), "+v"(b2), "+v"(b3));
    asm volatile("" : "+v"(b4), "+v"(b5), "+v"(b6), "+v"(b7));
    asm volatile("" : "+v"(o0), "+v"(o1), "+v"(o2), "+v"(o3));
    asm volatile("" : "+v"(o4), "+v"(o5), "+v"(o6), "+v"(o7));

    // A-frag read pointer (wave-uniform source select; lane-distinct address)
    const unsigned short* ap;
    if (wid < 5)      ap = &A0[0][0] + col * 136 + qrow * 8;
    else if (wid < 7) ap = &A1[0][0] + col * 136 + qrow * 8;
    else              ap = &Ax[0][0] + col * 72  + qrow * 8;

    // ---- assembly task descriptors (fixed per thread; h lives in registers) ----
    // tasks: A = tid (ll=0), B = tid+512 (ll = tid>=128), C = tid+1024 (tid<256, ll=1)
    const int taskA = tid;
    const int rA = taskA / 40, iA = taskA - rA * 40, eA = rA & 15;
    const int taskB = tid + NTHR;
    const int rB = taskB / 40, iB = taskB - rB * 40, eB = rB & 15, llB = rB >> 4;
    const bool hasC = tid < 256;
    const int taskC0 = tid + 2 * NTHR;
    const int taskC = taskC0 < 1280 ? taskC0 : 1279;
    const int rC = taskC / 40, iC = taskC - rC * 40, eC = rC & 15;

    const int gxA = eA * GSTR + 368 + iA, ghA = eA * GSTR + 0 + iA;          // ll=0
    const int gxB = eB * GSTR + (llB ? 120 : 368) + iB;
    const int ghB = eB * GSTR + (llB ? 240 : 0) + iB;
    const int gxC = eC * GSTR + 120 + iC, ghC = eC * GSTR + 240 + iC;        // ll=1
    unsigned short* paA = &A0[eA][iA];
    unsigned short* paB = (llB ? &A1[eB][iB] : &A0[eB][iB]);
    unsigned short* paC = &A1[eC][iC];
    float hA = 0.f, hB = 0.f, hC = 0.f;

#define ASTEP(gx, gh, pa, h) { \
    const float r_ = sigm(Gf[(gx)] + Gf[(gh)]); \
    const float z_ = sigm(Gf[(gx)+40] + Gf[(gh)+40]); \
    const float n_ = tanh_f(Gf[(gx)+80] + r_ * Gf[(gh)+80]); \
    h = (1.0f - z_) * n_ + z_ * h; \
    const unsigned short hb_ = bf16_rne(h); \
    const unsigned short lb_ = bf16_rne(h - bf16f(hb_)); \
    (pa)[0] = hb_; (pa)[40] = lb_; (pa)[80] = hb_; }

    // ---- init: zero A-buffers (pads must be 0), stage x[0], prefetch x[1] ----
    for (int idx = tid; idx < EPB * 136; idx += NTHR) { (&A0[0][0])[idx] = 0; (&A1[0][0])[idx] = 0; }
    for (int idx = tid; idx < EPB * 72;  idx += NTHR) (&Ax[0][0])[idx] = 0;
    __syncthreads();
    const bool xth = tid < 256;
    const int xe = tid >> 4, xk = tid & 15;
    const float* xrow = x + (size_t)(e0 + xe) * (T_STEPS * 16) + xk;
    float xold = 0.f;
    if (xth) {
        const float v = xrow[0];
        const unsigned short hb = bf16_rne(v);
        const unsigned short lb = bf16_rne(v - bf16f(hb));
        Ax[xe][xk] = hb; Ax[xe][16 + xk] = lb; Ax[xe][32 + xk] = hb;
        xold = xrow[16];
    }
    __syncthreads();

    for (int t = 0; t <= T_STEPS; ++t) {
        // prefetch x[t+2] (2-step-ahead: HBM latency never on critical path)
        float xnew = 0.f;
        if (xth && t + 2 < T_STEPS) xnew = xrow[(t + 2) * 16];

        // ---- dot phase (wave-specialized) ----
        f32x4 c;
        if (wid < 7) {
            const bf16x8 a0 = *(const bf16x8*)(ap);
            const bf16x8 a1 = *(const bf16x8*)(ap + 32);
            const bf16x8 a2 = *(const bf16x8*)(ap + 64);
            const bf16x8 a3 = *(const bf16x8*)(ap + 96);
            c = (f32x4){b0, b0, b0, b0};
            MF(a0, F00, c); MF(a1, F01, c); MF(a2, F02, c); MF(a3, F03, c);
            Gf[o0] = c[0]; Gf[o0+GSTR] = c[1]; Gf[o0+2*GSTR] = c[2]; Gf[o0+3*GSTR] = c[3];
            c = (f32x4){b1, b1, b1, b1};
            MF(a0, F10, c); MF(a1, F11, c); MF(a2, F12, c); MF(a3, F13, c);
            Gf[o1] = c[0]; Gf[o1+GSTR] = c[1]; Gf[o1+2*GSTR] = c[2]; Gf[o1+3*GSTR] = c[3];
            c = (f32x4){b2, b2, b2, b2};
            MF(a0, F20, c); MF(a1, F21, c); MF(a2, F22, c); MF(a3, F23, c);
            Gf[o2] = c[0]; Gf[o2+GSTR] = c[1]; Gf[o2+2*GSTR] = c[2]; Gf[o2+3*GSTR] = c[3];
            if (wid >= 5) {
                c = (f32x4){b3, b3, b3, b3};
                MF(a0, F30, c); MF(a1, F31, c); MF(a2, F32, c); MF(a3, F33, c);
                Gf[o3] = c[0]; Gf[o3+GSTR] = c[1]; Gf[o3+2*GSTR] = c[2]; Gf[o3+3*GSTR] = c[3];
            }
        } else {
            const bf16x8 a0 = *(const bf16x8*)(ap);
            const bf16x8 a1 = *(const bf16x8*)(ap + 32);
#define XT(Fa, Fb, bS, oS) \
            c = (f32x4){bS, bS, bS, bS}; \
            MF(a0, Fa, c); MF(a1, Fb, c); \
            Gf[oS] = c[0]; Gf[oS+GSTR] = c[1]; Gf[oS+2*GSTR] = c[2]; Gf[oS+3*GSTR] = c[3];
            XT(F00, F01, b0, o0) XT(F02, F03, b1, o1)
            XT(F10, F11, b2, o2) XT(F12, F13, b3, o3)
            XT(F20, F21, b4, o4) XT(F22, F23, b5, o5)
            XT(F30, F31, b6, o6) XT(F32, F33, b7, o7)
        }
        __syncthreads();

        // ---- assembly (register h-state; wave-uniform guards) ----
        if (t < T_STEPS)                  ASTEP(gxA, ghA, paA, hA);
        if (llB ? (t > 0) : (t < T_STEPS)) ASTEP(gxB, ghB, paB, hB);
        if (hasC && t > 0)                ASTEP(gxC, ghC, paC, hC);

        // stage x[t+1] from register
        if (xth && t < T_STEPS - 1) {
            const unsigned short hb = bf16_rne(xold);
            const unsigned short lb = bf16_rne(xold - bf16f(hb));
            Ax[xe][xk] = hb; Ax[xe][16 + xk] = lb; Ax[xe][32 + xk] = hb;
        }
        xold = xnew;
        __syncthreads();
    }

    // ---- output h1[255] straight from registers ----
    if (llB)  out[(size_t)(e0 + eB) * HID + iB] = hB;
    if (hasC) out[(size_t)(e0 + eC) * HID + iC] = hC;
}

extern "C" void kernel_launch(void* const* d_in, const int* in_sizes, int n_in,
                              void* d_out, int out_size, void* d_ws, size_t ws_size,
                              hipStream_t stream) {
    const float* x    = (const float*)d_in[0];
    const float* Wih0 = (const float*)d_in[1];
    const float* Whh0 = (const float*)d_in[2];
    const float* bih0 = (const float*)d_in[3];
    const float* bhh0 = (const float*)d_in[4];
    const float* Wih1 = (const float*)d_in[5];
    const float* Whh1 = (const float*)d_in[6];
    const float* bih1 = (const float*)d_in[7];
    const float* bhh1 = (const float*)d_in[8];
    float* out = (float*)d_out;

    dim3 grid(4096 / EPB), block(NTHR);
    hipLaunchKernelGGL(gru2_kernel, grid, block, 0, stream,
                       x, Wih0, Whh0, bih0, bhh0, Wih1, Whh1, bih1, bhh1, out);
}